// Round 1
// baseline (455.830 us; speedup 1.0000x reference)
//
#include <hip/hip_runtime.h>
#include <stdint.h>

// B=4, L=2048, E=1024, H=16, DK=64. Causal MHA forward, bf16 MFMA pipeline.
// ws layout (bytes): [0,16M) xb (aliased later by attn_out Ab), [16M,22M) wqb,
// [22M,24M) wob, [24M,40M) Q, [40M,56M) K, [56M,72M) Vt.   total 72 MB.

typedef __bf16 bf16;
typedef __bf16 bf16x4 __attribute__((ext_vector_type(4)));
typedef __bf16 bf16x8 __attribute__((ext_vector_type(8)));
typedef float floatx4 __attribute__((ext_vector_type(4)));

#define MFMA16(a, b, c) __builtin_amdgcn_mfma_f32_16x16x32_bf16(a, b, c, 0, 0, 0)

typedef const __attribute__((address_space(1))) uint32_t* gas_t;
typedef __attribute__((address_space(3))) uint32_t* las_t;

// async global->LDS, 16B per lane; lds base must be wave-uniform (HW adds lane*16)
__device__ __forceinline__ void async16(void* lds, const void* g) {
  __builtin_amdgcn_global_load_lds((gas_t)g, (las_t)lds, 16, 0, 0);
}

__global__ void f32_to_bf16(const float4* __restrict__ src, bf16x4* __restrict__ dst, int n4) {
  int i = blockIdx.x * blockDim.x + threadIdx.x;
  if (i < n4) {
    float4 v = src[i];
    bf16x4 o;
    o[0] = (bf16)v.x; o[1] = (bf16)v.y; o[2] = (bf16)v.z; o[3] = (bf16)v.w;
    dst[i] = o;
  }
}

// C[m,n] = sum_k A[m,k] * B[n,k].  A:[M,K], B:[N,K] bf16 row-major, K%32==0.
// MODE 1: qkv scatter epilogue (bf16 -> Qb/Kb/Vt).  MODE 2: fp32 store to Cf.
template <int MODE>
__global__ __launch_bounds__(256) void gemm_bt(
    const bf16* __restrict__ A, const bf16* __restrict__ B,
    float* __restrict__ Cf, bf16* __restrict__ Qb, bf16* __restrict__ Kb,
    bf16* __restrict__ Vt, int M, int N, int K) {
  __shared__ __align__(16) bf16 As[128 * 32];
  __shared__ __align__(16) bf16 Bs[128 * 32];
  const int tid = threadIdx.x;
  const int wave = tid >> 6, lane = tid & 63;
  const int wm = wave & 1, wn = wave >> 1;
  const int row0 = blockIdx.y * 128, col0 = blockIdx.x * 128;
  const int l15 = lane & 15, quad = lane >> 4;
  const int srow = lane >> 2;         // 0..15 within a 16-row chunk
  const int scol = (lane & 3) * 8;    // 0,8,16,24

  floatx4 acc[4][4] = {};

  for (int k0 = 0; k0 < K; k0 += 32) {
#pragma unroll
    for (int i = 0; i < 2; ++i) {
      int c = wave + i * 4;  // 8 chunks of 16 rows each
      async16(&As[c * 512], A + (size_t)(row0 + c * 16 + srow) * K + k0 + scol);
      async16(&Bs[c * 512], B + (size_t)(col0 + c * 16 + srow) * K + k0 + scol);
    }
    __syncthreads();
    bf16x8 af[4], bfr[4];
#pragma unroll
    for (int t = 0; t < 4; ++t) {
      af[t]  = *(const bf16x8*)&As[(wm * 64 + t * 16 + l15) * 32 + quad * 8];
      bfr[t] = *(const bf16x8*)&Bs[(wn * 64 + t * 16 + l15) * 32 + quad * 8];
    }
#pragma unroll
    for (int mt = 0; mt < 4; ++mt)
#pragma unroll
      for (int nt = 0; nt < 4; ++nt)
        acc[mt][nt] = MFMA16(af[mt], bfr[nt], acc[mt][nt]);
    __syncthreads();
  }

#pragma unroll
  for (int mt = 0; mt < 4; ++mt)
#pragma unroll
    for (int nt = 0; nt < 4; ++nt)
#pragma unroll
      for (int r = 0; r < 4; ++r) {
        int gr = row0 + wm * 64 + mt * 16 + quad * 4 + r;  // m (=b*L+l)
        int gc = col0 + wn * 64 + nt * 16 + l15;           // n
        float v = acc[mt][nt][r];
        if (MODE == 2) {
          Cf[(size_t)gr * N + gc] = v;
        } else {
          int t = gc >> 10, hd = gc & 1023;
          if (t == 0) {
            Qb[(size_t)gr * 1024 + hd] = (bf16)v;
          } else if (t == 1) {
            Kb[(size_t)gr * 1024 + hd] = (bf16)v;
          } else {
            int h = hd >> 6, d = hd & 63, bb = gr >> 11, l = gr & 2047;
            Vt[((((size_t)bb * 16 + h) * 64 + d) << 11) + l] = (bf16)v;
          }
        }
      }
}

// Flash attention, causal. One block per (b,h,qtile128). 4 waves, 32 q-rows/wave.
__global__ __launch_bounds__(256, 2) void flash_attn(
    const bf16* __restrict__ Qb, const bf16* __restrict__ Kb,
    const bf16* __restrict__ Vt, bf16* __restrict__ Ob) {
  const int bid = blockIdx.x;
  const int qi = 15 - (bid & 15);  // heavy tiles first
  const int bh = bid >> 4;         // b*16 + h
  const int b = bh >> 4, h = bh & 15;
  const int tid = threadIdx.x;
  const int wave = tid >> 6, lane = tid & 63;
  const int l15 = lane & 15, quad = lane >> 4;

  __shared__ __align__(16) bf16 Ks[128 * 64];      // [key][d]
  __shared__ __align__(16) bf16 Vs[64 * 128];      // [d][key]  (V^T tile)
  __shared__ __align__(16) bf16 Ps[4][32 * 72];    // per-wave P half-tile, padded

  const size_t x_base = (size_t)b * 2048 * 1024 + (size_t)h * 64;  // + l*1024 + d
  const size_t vt_base = (size_t)bh * 64 * 2048;                   // + d*2048 + l

  // Q fragments in registers, pre-scaled by 1/sqrt(64)=0.125 (exact in bf16)
  bf16x8 qf[2][2];
#pragma unroll
  for (int qt = 0; qt < 2; ++qt)
#pragma unroll
    for (int ks = 0; ks < 2; ++ks) {
      const bf16* p = Qb + x_base +
          (size_t)(qi * 128 + wave * 32 + qt * 16 + l15) * 1024 + ks * 32 + quad * 8;
      bf16x8 v = *(const bf16x8*)p;
#pragma unroll
      for (int j = 0; j < 8; ++j) v[j] = (bf16)((float)v[j] * 0.125f);
      qf[qt][ks] = v;
    }

  floatx4 o[2][4] = {};
  float m_run[2][4], l_run[2][4];
#pragma unroll
  for (int qt = 0; qt < 2; ++qt)
#pragma unroll
    for (int r = 0; r < 4; ++r) { m_run[qt][r] = -__builtin_inff(); l_run[qt][r] = 0.f; }

  bf16* Pl = &Ps[wave][0];

  for (int kt = 0; kt <= qi; ++kt) {
    {  // stage K tile [128][64] and V^T tile [64][128], 16 chunks each, 4/wave
      const int kr = lane >> 3, kc = (lane & 7) * 8;
      const int vr = lane >> 4, vc = (lane & 15) * 8;
#pragma unroll
      for (int i = 0; i < 4; ++i) {
        int c = wave * 4 + i;
        async16(&Ks[c * 512],
                Kb + x_base + (size_t)(kt * 128 + c * 8 + kr) * 1024 + kc);
        async16(&Vs[c * 512],
                Vt + vt_base + (size_t)(c * 4 + vr) * 2048 + kt * 128 + vc);
      }
    }
    __syncthreads();

    // S = Q K^T  (wave computes [32 q][128 keys])
    floatx4 s[2][8] = {};
#pragma unroll
    for (int ks = 0; ks < 2; ++ks) {
      bf16x8 kbf[8];
#pragma unroll
      for (int nt = 0; nt < 8; ++nt)
        kbf[nt] = *(const bf16x8*)&Ks[(nt * 16 + l15) * 64 + ks * 32 + quad * 8];
#pragma unroll
      for (int qt = 0; qt < 2; ++qt)
#pragma unroll
        for (int nt = 0; nt < 8; ++nt)
          s[qt][nt] = MFMA16(qf[qt][ks], kbf[nt], s[qt][nt]);
    }

    if (kt == qi) {  // causal mask on diagonal tile
#pragma unroll
      for (int qt = 0; qt < 2; ++qt)
#pragma unroll
        for (int nt = 0; nt < 8; ++nt)
#pragma unroll
          for (int r = 0; r < 4; ++r) {
            int ql = wave * 32 + qt * 16 + quad * 4 + r;
            int kl = nt * 16 + l15;
            if (kl > ql) s[qt][nt][r] = -__builtin_inff();
          }
    }

    // online softmax; row lives across the 16 lanes sharing `quad`
    float alpha[2][4];
#pragma unroll
    for (int qt = 0; qt < 2; ++qt)
#pragma unroll
      for (int r = 0; r < 4; ++r) {
        float mloc = s[qt][0][r];
#pragma unroll
        for (int nt = 1; nt < 8; ++nt) mloc = fmaxf(mloc, s[qt][nt][r]);
#pragma unroll
        for (int off = 1; off < 16; off <<= 1)
          mloc = fmaxf(mloc, __shfl_xor(mloc, off));
        float m_new = fmaxf(m_run[qt][r], mloc);
        alpha[qt][r] = __expf(m_run[qt][r] - m_new);  // exp(-inf)=0 first iter
        m_run[qt][r] = m_new;
        float lsum = 0.f;
#pragma unroll
        for (int nt = 0; nt < 8; ++nt) {
          float p = __expf(s[qt][nt][r] - m_new);
          s[qt][nt][r] = p;
          lsum += p;
        }
#pragma unroll
        for (int off = 1; off < 16; off <<= 1) lsum += __shfl_xor(lsum, off);
        l_run[qt][r] = alpha[qt][r] * l_run[qt][r] + lsum;
      }

    // rescale O
#pragma unroll
    for (int qt = 0; qt < 2; ++qt)
#pragma unroll
      for (int dt = 0; dt < 4; ++dt)
#pragma unroll
        for (int r = 0; r < 4; ++r) o[qt][dt][r] *= alpha[qt][r];

    // P@V in two 64-key halves through wave-private LDS (layout conversion)
#pragma unroll
    for (int half = 0; half < 2; ++half) {
#pragma unroll
      for (int qt = 0; qt < 2; ++qt)
#pragma unroll
        for (int j = 0; j < 4; ++j)
#pragma unroll
          for (int r = 0; r < 4; ++r)
            Pl[(qt * 16 + quad * 4 + r) * 72 + j * 16 + l15] =
                (bf16)s[qt][half * 4 + j][r];
#pragma unroll
      for (int ss = 0; ss < 2; ++ss) {
        bf16x8 pf[2], vf[4];
#pragma unroll
        for (int qt = 0; qt < 2; ++qt)
          pf[qt] = *(const bf16x8*)&Pl[(qt * 16 + l15) * 72 + ss * 32 + quad * 8];
#pragma unroll
        for (int dt = 0; dt < 4; ++dt)
          vf[dt] = *(const bf16x8*)&Vs[(dt * 16 + l15) * 128 +
                                       (half * 2 + ss) * 32 + quad * 8];
#pragma unroll
        for (int qt = 0; qt < 2; ++qt)
#pragma unroll
          for (int dt = 0; dt < 4; ++dt)
            o[qt][dt] = MFMA16(pf[qt], vf[dt], o[qt][dt]);
      }
    }
    __syncthreads();  // Ks/Vs reused next kt
  }

  // epilogue: O/l -> attn_out [b*L+l][h*64+d] bf16
#pragma unroll
  for (int qt = 0; qt < 2; ++qt)
#pragma unroll
    for (int dt = 0; dt < 4; ++dt)
#pragma unroll
      for (int r = 0; r < 4; ++r) {
        float v = o[qt][dt][r] / l_run[qt][r];
        size_t row = (size_t)(qi * 128 + wave * 32 + qt * 16 + quad * 4 + r);
        Ob[x_base + row * 1024 + dt * 16 + l15] = (bf16)v;
      }
}

extern "C" void kernel_launch(void* const* d_in, const int* in_sizes, int n_in,
                              void* d_out, int out_size, void* d_ws, size_t ws_size,
                              hipStream_t stream) {
  const float* x     = (const float*)d_in[0];
  // d_in[1] = causal mask, hardcoded
  const float* w_qkv = (const float*)d_in[2];
  const float* wo    = (const float*)d_in[3];
  float* out = (float*)d_out;

  char* ws = (char*)d_ws;
  bf16* xb  = (bf16*)(ws);                        // 16 MB
  bf16* wqb = (bf16*)(ws + (16u << 20));          // 6 MB
  bf16* wob = (bf16*)(ws + (22u << 20));          // 2 MB
  bf16* Qb  = (bf16*)(ws + (24u << 20));          // 16 MB
  bf16* Kb  = (bf16*)(ws + (40u << 20));          // 16 MB
  bf16* Vt  = (bf16*)(ws + (56u << 20));          // 16 MB
  bf16* Ab  = (bf16*)(ws);                        // aliases xb (dead after GEMM1)

  const int nx = 8192 * 1024, nq = 3072 * 1024, no = 1024 * 1024;
  f32_to_bf16<<<(nx / 4 + 255) / 256, 256, 0, stream>>>((const float4*)x, (bf16x4*)xb, nx / 4);
  f32_to_bf16<<<(nq / 4 + 255) / 256, 256, 0, stream>>>((const float4*)w_qkv, (bf16x4*)wqb, nq / 4);
  f32_to_bf16<<<(no / 4 + 255) / 256, 256, 0, stream>>>((const float4*)wo, (bf16x4*)wob, no / 4);

  gemm_bt<1><<<dim3(24, 64), 256, 0, stream>>>(xb, wqb, nullptr, Qb, Kb, Vt,
                                               8192, 3072, 1024);
  flash_attn<<<1024, 256, 0, stream>>>(Qb, Kb, Vt, Ab);
  gemm_bt<2><<<dim3(8, 64), 256, 0, stream>>>(Ab, wob, out, nullptr, nullptr,
                                              nullptr, 8192, 1024, 1024);
}

// Round 2
// 340.506 us; speedup vs baseline: 1.3387x; 1.3387x over previous
//
#include <hip/hip_runtime.h>
#include <stdint.h>

// B=4, L=2048, E=1024, H=16, DK=64. Causal MHA forward, bf16 MFMA pipeline.
// ws layout (bytes): [0,16M) xb (aliased later by attn_out Ab), [16M,22M) wqb,
// [22M,24M) wob, [24M,40M) Q, [40M,56M) K, [56M,72M) Vt.   total 72 MB.

typedef __bf16 bf16;
typedef __bf16 bf16x4 __attribute__((ext_vector_type(4)));
typedef __bf16 bf16x8 __attribute__((ext_vector_type(8)));
typedef float floatx4 __attribute__((ext_vector_type(4)));
typedef short s16x4 __attribute__((ext_vector_type(4)));

#define MFMA32(a, b, c) __builtin_amdgcn_mfma_f32_16x16x32_bf16(a, b, c, 0, 0, 0)
#define MFMA16(a, b, c) __builtin_amdgcn_mfma_f32_16x16x16bf16_1k(a, b, c, 0, 0, 0)

typedef const __attribute__((address_space(1))) uint32_t* gas_t;
typedef __attribute__((address_space(3))) uint32_t* las_t;

// async global->LDS, 16B per lane; lds base must be wave-uniform (HW adds lane*16)
__device__ __forceinline__ void async16(void* lds, const void* g) {
  __builtin_amdgcn_global_load_lds((gas_t)g, (las_t)lds, 16, 0, 0);
}

__global__ void f32_to_bf16(const float4* __restrict__ src, bf16x4* __restrict__ dst, int n4) {
  int i = blockIdx.x * blockDim.x + threadIdx.x;
  if (i < n4) {
    float4 v = src[i];
    bf16x4 o;
    o[0] = (bf16)v.x; o[1] = (bf16)v.y; o[2] = (bf16)v.z; o[3] = (bf16)v.w;
    dst[i] = o;
  }
}

// C[m,n] = sum_k A[m,k] * B[n,k].  A:[M,K], B:[N,K] bf16 row-major, K%32==0.
// MODE 1: qkv scatter epilogue (bf16 -> Qb/Kb/Vt).  MODE 2: fp32 store to Cf.
template <int MODE>
__global__ __launch_bounds__(256) void gemm_bt(
    const bf16* __restrict__ A, const bf16* __restrict__ B,
    float* __restrict__ Cf, bf16* __restrict__ Qb, bf16* __restrict__ Kb,
    bf16* __restrict__ Vt, int M, int N, int K) {
  __shared__ __align__(16) bf16 As[128 * 32];
  __shared__ __align__(16) bf16 Bs[128 * 32];
  const int tid = threadIdx.x;
  const int wave = tid >> 6, lane = tid & 63;
  const int wm = wave & 1, wn = wave >> 1;
  const int row0 = blockIdx.y * 128, col0 = blockIdx.x * 128;
  const int l15 = lane & 15, quad = lane >> 4;
  const int srow = lane >> 2;         // 0..15 within a 16-row chunk
  const int scol = (lane & 3) * 8;    // 0,8,16,24

  floatx4 acc[4][4] = {};

  for (int k0 = 0; k0 < K; k0 += 32) {
#pragma unroll
    for (int i = 0; i < 2; ++i) {
      int c = wave + i * 4;  // 8 chunks of 16 rows each
      async16(&As[c * 512], A + (size_t)(row0 + c * 16 + srow) * K + k0 + scol);
      async16(&Bs[c * 512], B + (size_t)(col0 + c * 16 + srow) * K + k0 + scol);
    }
    __syncthreads();
    bf16x8 af[4], bfr[4];
#pragma unroll
    for (int t = 0; t < 4; ++t) {
      af[t]  = *(const bf16x8*)&As[(wm * 64 + t * 16 + l15) * 32 + quad * 8];
      bfr[t] = *(const bf16x8*)&Bs[(wn * 64 + t * 16 + l15) * 32 + quad * 8];
    }
#pragma unroll
    for (int mt = 0; mt < 4; ++mt)
#pragma unroll
      for (int nt = 0; nt < 4; ++nt)
        acc[mt][nt] = MFMA32(af[mt], bfr[nt], acc[mt][nt]);
    __syncthreads();
  }

#pragma unroll
  for (int mt = 0; mt < 4; ++mt)
#pragma unroll
    for (int nt = 0; nt < 4; ++nt)
#pragma unroll
      for (int r = 0; r < 4; ++r) {
        int gr = row0 + wm * 64 + mt * 16 + quad * 4 + r;  // m (=b*L+l)
        int gc = col0 + wn * 64 + nt * 16 + l15;           // n
        float v = acc[mt][nt][r];
        if (MODE == 2) {
          Cf[(size_t)gr * N + gc] = v;
        } else {
          int t = gc >> 10, hd = gc & 1023;
          if (t == 0) {
            Qb[(size_t)gr * 1024 + hd] = (bf16)v;
          } else if (t == 1) {
            Kb[(size_t)gr * 1024 + hd] = (bf16)v;
          } else {
            int h = hd >> 6, d = hd & 63, bb = gr >> 11, l = gr & 2047;
            Vt[((((size_t)bb * 16 + h) * 64 + d) << 11) + l] = (bf16)v;
          }
        }
      }
}

// Flash attention, causal. One block per (b,h,qtile128). 4 waves, 32 q-rows/wave.
// Computes S^T = K·Q^T so softmax stats are per-lane-column (l15=q) and P^T is
// already in the B-operand layout of mfma_16x16x16 -> no LDS round-trip for P.
// K/V^T LDS tiles are XOR-swizzled at staging time (16B-chunk granularity, so
// async16 sources stay contiguous) to put all ds_reads at the bank floor.
__global__ __launch_bounds__(256, 3) void flash_attn(
    const bf16* __restrict__ Qb, const bf16* __restrict__ Kb,
    const bf16* __restrict__ Vt, bf16* __restrict__ Ob) {
  const int bid = blockIdx.x;
  const int qi = 15 - (bid & 15);  // heavy tiles first
  const int bh = bid >> 4;         // b*16 + h
  const int b = bh >> 4, h = bh & 15;
  const int tid = threadIdx.x;
  const int wave = tid >> 6, lane = tid & 63;
  const int l15 = lane & 15, quad = lane >> 4;

  __shared__ __align__(16) bf16 Ks[128 * 64];  // [key][d], 16B chunks ^ (key&7)
  __shared__ __align__(16) bf16 Vs[64 * 128];  // [d][key], 16B chunks ^ (d&15)

  const size_t x_base = (size_t)b * 2048 * 1024 + (size_t)h * 64;  // + l*1024 + d
  const size_t vt_base = (size_t)bh * 64 * 2048;                   // + d*2048 + l

  // Q fragments (B-operand: [n=q=l15][k=d=quad*8+j]), pre-scaled by 1/8 exact
  bf16x8 qf[2][2];
#pragma unroll
  for (int qt = 0; qt < 2; ++qt)
#pragma unroll
    for (int ks = 0; ks < 2; ++ks) {
      const bf16* p = Qb + x_base +
          (size_t)(qi * 128 + wave * 32 + qt * 16 + l15) * 1024 + ks * 32 + quad * 8;
      bf16x8 v = *(const bf16x8*)p;
#pragma unroll
      for (int j = 0; j < 8; ++j) v[j] = (bf16)((float)v[j] * 0.125f);
      qf[qt][ks] = v;
    }

  floatx4 o[2][4] = {};                       // O^T: [d=dt*16+quad*4+r][q=l15]
  float m_run[2], l_run[2];
#pragma unroll
  for (int qt = 0; qt < 2; ++qt) { m_run[qt] = -__builtin_inff(); l_run[qt] = 0.f; }

  // staging geometry (per-lane, loop-invariant)
  const int k_lr = lane >> 3, k_c = lane & 7;    // K: row-in-8, chunk 0..7
  const int v_lr = lane >> 4, v_c = lane & 15;   // V: row-in-4, chunk 0..15

  for (int kt = 0; kt <= qi; ++kt) {
    // stage K tile [128][64] and V^T tile [64][128]; 32 async16 ops, 8/wave
#pragma unroll
    for (int i = 0; i < 4; ++i) {
      int o8 = wave * 4 + i;
      int krow = o8 * 8 + k_lr;                          // key 0..127
      async16(&Ks[o8 * 512],
              Kb + x_base + (size_t)(kt * 128 + krow) * 1024 + ((k_c ^ (krow & 7)) << 3));
      int vrow = o8 * 4 + v_lr;                          // d 0..63
      async16(&Vs[o8 * 512],
              Vt + vt_base + (size_t)vrow * 2048 + kt * 128 + ((v_c ^ (vrow & 15)) << 3));
    }
    __syncthreads();

    // S^T = K Q^T : s[qt][nt] holds S^T[key=nt*16+quad*4+r][q=qt*16+l15]
    floatx4 s[2][8] = {};
#pragma unroll
    for (int nt = 0; nt < 8; ++nt) {
      int krow = nt * 16 + l15;
#pragma unroll
      for (int ks = 0; ks < 2; ++ks) {
        bf16x8 kf = *(const bf16x8*)&Ks[krow * 64 + ((((ks << 2) | quad) ^ (l15 & 7)) << 3)];
        s[0][nt] = MFMA32(kf, qf[0][ks], s[0][nt]);
        s[1][nt] = MFMA32(kf, qf[1][ks], s[1][nt]);
      }
    }

    if (kt == qi) {  // causal mask on diagonal tile: mask keys > q
#pragma unroll
      for (int qt = 0; qt < 2; ++qt) {
        int q_in_tile = wave * 32 + qt * 16 + l15;
#pragma unroll
        for (int nt = 0; nt < 8; ++nt)
#pragma unroll
          for (int r = 0; r < 4; ++r)
            if (nt * 16 + quad * 4 + r > q_in_tile) s[qt][nt][r] = -__builtin_inff();
      }
    }

    // online softmax; stats per q = per l15 column: in-lane over 32 keys,
    // then 2 shfl_xor across the 4 quads
    float alpha[2];
#pragma unroll
    for (int qt = 0; qt < 2; ++qt) {
      float mloc = -__builtin_inff();
#pragma unroll
      for (int nt = 0; nt < 8; ++nt)
#pragma unroll
        for (int r = 0; r < 4; ++r) mloc = fmaxf(mloc, s[qt][nt][r]);
      mloc = fmaxf(mloc, __shfl_xor(mloc, 16));
      mloc = fmaxf(mloc, __shfl_xor(mloc, 32));
      float m_new = fmaxf(m_run[qt], mloc);
      alpha[qt] = __expf(m_run[qt] - m_new);  // exp(-inf)=0 on first iter
      m_run[qt] = m_new;
      float ls = 0.f;
#pragma unroll
      for (int nt = 0; nt < 8; ++nt)
#pragma unroll
        for (int r = 0; r < 4; ++r) {
          float p = __expf(s[qt][nt][r] - m_new);
          s[qt][nt][r] = p;
          ls += p;
        }
      ls += __shfl_xor(ls, 16);
      ls += __shfl_xor(ls, 32);
      l_run[qt] = alpha[qt] * l_run[qt] + ls;
#pragma unroll
      for (int dt = 0; dt < 4; ++dt)
#pragma unroll
        for (int r = 0; r < 4; ++r) o[qt][dt][r] *= alpha[qt];
    }

    // O^T += V^T · P^T via mfma_16x16x16: P fragment (k=quad*4+r) is the raw
    // softmaxed C-block — no LDS, no shuffles. V^T frag from swizzled Vs.
#pragma unroll
    for (int kb = 0; kb < 8; ++kb) {
      int c16 = (((kb << 1) | (quad >> 1)) ^ l15) & 15;
      s16x4 vf[4];
#pragma unroll
      for (int dt = 0; dt < 4; ++dt)
        vf[dt] = *(const s16x4*)&Vs[(dt * 16 + l15) * 128 + (c16 << 3) + ((quad & 1) << 2)];
#pragma unroll
      for (int qt = 0; qt < 2; ++qt) {
        bf16x4 pb;
#pragma unroll
        for (int r = 0; r < 4; ++r) pb[r] = (bf16)s[qt][kb][r];
        s16x4 pf = __builtin_bit_cast(s16x4, pb);
#pragma unroll
        for (int dt = 0; dt < 4; ++dt)
          o[qt][dt] = MFMA16(vf[dt], pf, o[qt][dt]);
      }
    }
    __syncthreads();  // Ks/Vs reused next kt
  }

  // epilogue: O^T/l -> attn_out [b*L+l][h*64+d]; 4 consecutive d per lane -> 8B stores
#pragma unroll
  for (int qt = 0; qt < 2; ++qt) {
    float inv = 1.0f / l_run[qt];
    size_t rowoff = x_base + (size_t)(qi * 128 + wave * 32 + qt * 16 + l15) * 1024;
#pragma unroll
    for (int dt = 0; dt < 4; ++dt) {
      bf16x4 ob;
#pragma unroll
      for (int r = 0; r < 4; ++r) ob[r] = (bf16)(o[qt][dt][r] * inv);
      *(bf16x4*)(Ob + rowoff + dt * 16 + quad * 4) = ob;
    }
  }
}

extern "C" void kernel_launch(void* const* d_in, const int* in_sizes, int n_in,
                              void* d_out, int out_size, void* d_ws, size_t ws_size,
                              hipStream_t stream) {
  const float* x     = (const float*)d_in[0];
  // d_in[1] = causal mask, hardcoded
  const float* w_qkv = (const float*)d_in[2];
  const float* wo    = (const float*)d_in[3];
  float* out = (float*)d_out;

  char* ws = (char*)d_ws;
  bf16* xb  = (bf16*)(ws);                        // 16 MB
  bf16* wqb = (bf16*)(ws + (16u << 20));          // 6 MB
  bf16* wob = (bf16*)(ws + (22u << 20));          // 2 MB
  bf16* Qb  = (bf16*)(ws + (24u << 20));          // 16 MB
  bf16* Kb  = (bf16*)(ws + (40u << 20));          // 16 MB
  bf16* Vt  = (bf16*)(ws + (56u << 20));          // 16 MB
  bf16* Ab  = (bf16*)(ws);                        // aliases xb (dead after GEMM1)

  const int nx = 8192 * 1024, nq = 3072 * 1024, no = 1024 * 1024;
  f32_to_bf16<<<(nx / 4 + 255) / 256, 256, 0, stream>>>((const float4*)x, (bf16x4*)xb, nx / 4);
  f32_to_bf16<<<(nq / 4 + 255) / 256, 256, 0, stream>>>((const float4*)w_qkv, (bf16x4*)wqb, nq / 4);
  f32_to_bf16<<<(no / 4 + 255) / 256, 256, 0, stream>>>((const float4*)wo, (bf16x4*)wob, no / 4);

  gemm_bt<1><<<dim3(24, 64), 256, 0, stream>>>(xb, wqb, nullptr, Qb, Kb, Vt,
                                               8192, 3072, 1024);
  flash_attn<<<1024, 256, 0, stream>>>(Qb, Kb, Vt, Ab);
  gemm_bt<2><<<dim3(8, 64), 256, 0, stream>>>(Ab, wob, out, nullptr, nullptr,
                                              nullptr, 8192, 1024, 1024);
}